// Round 1
// 129.053 us; speedup vs baseline: 1.1710x; 1.1710x over previous
//
#include <hip/hip_runtime.h>
#include <hip/hip_fp16.h>

#define D 512
#define NTOK 512
#define BINS 64

typedef float v4f __attribute__((ext_vector_type(4)));
typedef int v4i __attribute__((ext_vector_type(4)));
typedef short short8 __attribute__((ext_vector_type(8)));
typedef _Float16 h8 __attribute__((ext_vector_type(8)));
typedef _Float16 h4 __attribute__((ext_vector_type(4)));

// packed f16 tanh-approx gelu: x * sigmoid(1.5957691x + 0.0713548x^3), exp2 form.
// f16 saturation gives correct limits: e=inf -> rcp=0 -> gelu=0 (x<<0);
// e->0 -> rcp(1)=1 -> gelu=x (x>>0).
__device__ __forceinline__ __half2 gelu2(__half2 x) {
    __half2 s = __hmul2(x, x);
    __half2 q = __hmul2(x, __hfma2(s, __float2half2_rn(-0.1029437f),
                                      __float2half2_rn(-2.3022082f)));
    __half2 e = h2exp2(q);
    __half2 r = h2rcp(__hadd2(e, __float2half2_rn(1.0f)));
    return __hmul2(x, r);
}

__device__ __forceinline__ __half2 bc_h2(int v) { return __builtin_bit_cast(__half2, v); }
__device__ __forceinline__ int bc_i(__half2 v) { return __builtin_bit_cast(int, v); }

__device__ __forceinline__ v4i pack8(v4f a, v4f b) {
    h8 o;
    o[0] = (_Float16)a.x; o[1] = (_Float16)a.y; o[2] = (_Float16)a.z; o[3] = (_Float16)a.w;
    o[4] = (_Float16)b.x; o[5] = (_Float16)b.y; o[6] = (_Float16)b.z; o[7] = (_Float16)b.w;
    return __builtin_bit_cast(v4i, o);
}

// Operand packing for the MFMA projection GEMM (and the W2 fragments k_main uses).
// MFMA 16x16x32 f16 fragment layouts (verified lane maps):
//   A-frag: lane l holds A[l&15][(l>>4)*8 + j], j=0..7  (row-major 8 contiguous k)
//   B-frag: lane l holds B[(l>>4)*8 + j][l&15]          (k-major per out-col)
//   D:      col = l&15, row = (l>>4)*4 + reg
// Blocks 0..31:  Ap[rb][ks][l]  = f16(x[rb*16 + (l&15)][ks*32 + (l>>4)*8 .. +8])
// Blocks 32..95: Wp[nb][ks][l]  = f16(W1c[ks*32+(l>>4)*8+j][nb*16+(l&15)]) where
//                W1c[k][n] = W1[(n>=512 ? 512+k : k)*512 + (n&511)]  (k-major gather;
//                16 lanes read 16 consecutive n of one k-row -> 64B coalesced segs)
// Blocks 96..111: W2 -> Bp fragment pack (unchanged from previous k_proj).
__global__ __launch_bounds__(256) void k_pack(const float* __restrict__ x,
                                              const float* __restrict__ W1,
                                              const float* __restrict__ W2,
                                              v4i* __restrict__ Ap,
                                              v4i* __restrict__ Wp,
                                              short8* __restrict__ Bp) {
    const int b = blockIdx.x;
    const int t = threadIdx.x;
    if (b < 32) {            // x fragments: 32 rb x 16 ks x 64 lanes
        const int rb = b;
#pragma unroll
        for (int u = 0; u < 4; ++u) {
            const int e = t + 256 * u;           // 0..1023
            const int l = e & 63, ks = e >> 6;
            const float* src = x + (size_t)(rb * 16 + (l & 15)) * D + ks * 32 + (l >> 4) * 8;
            v4f a = *(const v4f*)src;
            v4f c = *(const v4f*)(src + 4);
            Ap[(size_t)(rb * 16 + ks) * 64 + l] = pack8(a, c);
        }
    } else if (b < 96) {     // W1 fragments: 64 nb x 16 ks x 64 lanes
        const int nb = b - 32;
#pragma unroll
        for (int u = 0; u < 4; ++u) {
            const int e = t + 256 * u;
            const int l = e & 63, ks = e >> 6;
            const int ng = nb * 16 + (l & 15);   // combined out col 0..1023
            const float* src = W1 + (size_t)((ng >> 9) * D + ks * 32 + (l >> 4) * 8) * D
                                  + (ng & 511);
            h8 o;
#pragma unroll
            for (int j = 0; j < 8; ++j) o[j] = (_Float16)src[(size_t)j * D];  // RTE
            Wp[(size_t)(nb * 16 + ks) * 64 + l] = __builtin_bit_cast(v4i, o);
        }
    } else {                 // W2 -> Bp (identical to previous session's pack)
        const int tid = (b - 96) * 256 + t;      // 0..4095
        const int ll = tid & 63;
        const int nt = (tid >> 6) & 3;
        const int kt = tid >> 8;
        const int colp = nt * 16 + (ll & 15);
        const int krow = kt * 32 + (ll >> 4) * 8;
        short8 v;
#pragma unroll
        for (int u = 0; u < 8; ++u) {
            _Float16 hv = (_Float16)W2[(size_t)(krow + u) * BINS + colp];  // RTE
            v[u] = __builtin_bit_cast(short, hv);
        }
        Bp[tid] = v;
    }
}

// Projection GEMM via MFMA on pre-packed fragments. H[512,1024] = x @ [W1a|W1b].
// Grid 256 = 16 mb (32 token rows) x 16 cb (64 out cols). 4 waves; wave w owns
// n-frag nb = cb*4+w, two m-frags (rb0, rb1). No LDS, no barriers: all operand
// traffic is 16B L2-hot fragment loads (Ap reused by 16 col-blocks, Wp by 16
// row-blocks). 32 MFMA/wave, f32 accum, +b1 on the hi half, f16 RTE store.
__global__ __launch_bounds__(256) void k_gemm(const v4i* __restrict__ Ap,
                                              const v4i* __restrict__ Wp,
                                              const float* __restrict__ b1,
                                              _Float16* __restrict__ hi,
                                              _Float16* __restrict__ hj) {
    const int l = threadIdx.x & 63;
    const int w = threadIdx.x >> 6;
    const int c = l & 15;
    const int q = l >> 4;
    const int mb = blockIdx.x >> 4;
    const int cb = blockIdx.x & 15;
    const int nb = cb * 4 + w;

    const v4i* ap0 = Ap + (size_t)(mb * 2 + 0) * 16 * 64 + l;
    const v4i* ap1 = Ap + (size_t)(mb * 2 + 1) * 16 * 64 + l;
    const v4i* wp  = Wp + (size_t)nb * 16 * 64 + l;

    v4f acc0 = {0.f, 0.f, 0.f, 0.f};
    v4f acc1 = {0.f, 0.f, 0.f, 0.f};
#pragma unroll 4
    for (int ks = 0; ks < 16; ++ks) {
        v4i a0 = ap0[ks * 64];
        v4i a1 = ap1[ks * 64];
        v4i bb = wp[ks * 64];
        h8 bf = __builtin_bit_cast(h8, bb);
        acc0 = __builtin_amdgcn_mfma_f32_16x16x32_f16(__builtin_bit_cast(h8, a0), bf, acc0, 0, 0, 0);
        acc1 = __builtin_amdgcn_mfma_f32_16x16x32_f16(__builtin_bit_cast(h8, a1), bf, acc1, 0, 0, 0);
    }

    const int ng = nb * 16 + c;                 // combined out col (one half per nb)
    const float b1v = (ng < D) ? b1[ng] : 0.0f;
    _Float16* dst = (ng < D ? hi : hj) + (ng & 511);
#pragma unroll
    for (int mf = 0; mf < 2; ++mf) {
        v4f acc = mf ? acc1 : acc0;
        const int row0 = mb * 32 + mf * 16 + q * 4;
#pragma unroll
        for (int r = 0; r < 4; ++r)
            dst[(size_t)(row0 + r) * D] = (_Float16)(acc[r] + b1v);
    }
}

// Main fused kernel: grid 1024; tile 16i x 16j, 4 waves, 4 i-rows/wave.
// f16 hi/hj staged per 64-k chunk in LDS; packed-f16 gelu feeds f16 MFMA directly.
// (UNCHANGED from the 151 µs version — isolates the proj-path delta.)
__global__ __launch_bounds__(256) void k_main(const __half* __restrict__ hi,
                                              const __half* __restrict__ hj,
                                              const v4i* __restrict__ Bp,
                                              const float* __restrict__ b2,
                                              float* __restrict__ out) {
    const int l = threadIdx.x & 63;
    const int w = threadIdx.x >> 6;
    const int c = l & 15;   // MFMA col: A m-index (j-offset) / B,D n-offset
    const int q = l >> 4;   // quad: k-group for A/B, row-group for D
    const int ib = (blockIdx.x >> 5) * 16;
    const int j0 = (blockIdx.x & 31) * 16;

    __shared__ __align__(16) short hic[16][72];  // 72 f16 row stride (16B-aligned rows)
    __shared__ __align__(16) short hjc[16][72];

    const int t = threadIdx.x;
    const int lr = (t & 127) >> 3;      // 0..15
    const int lc = (t & 7) * 8;         // f16 col 0..56
    const __half* gsrc = (t < 128 ? hi + (size_t)(ib + lr) * D
                                  : hj + (size_t)(j0 + lr) * D) + lc;
    short* ldst = (t < 128 ? &hic[lr][lc] : &hjc[lr][lc]);

    v4f acc[4][4] = {};  // [p(i)][nt]
    v4i pf = *(const v4i*)gsrc;  // prefetch chunk 0 (16B = 8 f16)

    for (int chunk = 0; chunk < 8; ++chunk) {
        *(v4i*)ldst = pf;
        __syncthreads();
        if (chunk < 7) pf = *(const v4i*)(gsrc + (chunk + 1) * 64);
        const int kt4 = chunk * 8;
#pragma unroll
        for (int h = 0; h < 2; ++h) {
            const int ko = h * 32 + q * 8;
            v4i hjraw = *(const v4i*)&hjc[c][ko];
            __half2 j0h = bc_h2(hjraw.x), j1h = bc_h2(hjraw.y);
            __half2 j2h = bc_h2(hjraw.z), j3h = bc_h2(hjraw.w);
            v4i bfr[4];
#pragma unroll
            for (int nt = 0; nt < 4; ++nt)
                bfr[nt] = Bp[(kt4 + h * 4 + nt) * 64 + l];
#pragma unroll
            for (int p = 0; p < 4; ++p) {
                v4i ar = *(const v4i*)&hic[w * 4 + p][ko];
                __half2 g0 = gelu2(__hadd2(bc_h2(ar.x), j0h));
                __half2 g1 = gelu2(__hadd2(bc_h2(ar.y), j1h));
                __half2 g2 = gelu2(__hadd2(bc_h2(ar.z), j2h));
                __half2 g3 = gelu2(__hadd2(bc_h2(ar.w), j3h));
                v4i ai = {bc_i(g0), bc_i(g1), bc_i(g2), bc_i(g3)};
                h8 af = __builtin_bit_cast(h8, ai);
#pragma unroll
                for (int nt = 0; nt < 4; ++nt)
                    acc[p][nt] = __builtin_amdgcn_mfma_f32_16x16x32_f16(
                        af, __builtin_bit_cast(h8, bfr[nt]), acc[p][nt], 0, 0, 0);
            }
        }
        __syncthreads();
    }

    const int i0 = ib + w * 4;
#pragma unroll
    for (int p = 0; p < 4; ++p) {
        const size_t rowbase = ((size_t)(i0 + p) * NTOK + j0 + q * 4) * BINS;
#pragma unroll
        for (int nt = 0; nt < 4; ++nt) {
            const float bb = b2[nt * 16 + c];
            float* op = out + rowbase + nt * 16 + c;
#pragma unroll
            for (int rr = 0; rr < 4; ++rr)
                op[(size_t)rr * BINS] = acc[p][nt][rr] + bb;
        }
    }
}

extern "C" void kernel_launch(void* const* d_in, const int* in_sizes, int n_in,
                              void* d_out, int out_size, void* d_ws, size_t ws_size,
                              hipStream_t stream) {
    const float* x  = (const float*)d_in[0];
    const float* W1 = (const float*)d_in[1];
    const float* b1 = (const float*)d_in[2];
    const float* W2 = (const float*)d_in[3];
    const float* b2 = (const float*)d_in[4];
    float* out = (float*)d_out;

    char* ws = (char*)d_ws;
    __half* hi = (__half*)ws;                          // 512 KB
    __half* hj = (__half*)(ws + (512u << 10));         // 512 KB
    short8* Bp = (short8*)(ws + (1u << 20));           // 64 KB
    v4i*    Ap = (v4i*)(ws + (1u << 20) + (64u << 10));            // 512 KB
    v4i*    Wp = (v4i*)(ws + (1u << 20) + (64u << 10) + (512u << 10));  // 1 MB

    k_pack<<<112, 256, 0, stream>>>(x, W1, W2, Ap, Wp, Bp);
    k_gemm<<<256, 256, 0, stream>>>(Ap, Wp, b1, (_Float16*)hi, (_Float16*)hj);
    k_main<<<1024, 256, 0, stream>>>(hi, hj, (const v4i*)Bp, b2, out);
}

// Round 2
// 127.418 us; speedup vs baseline: 1.1860x; 1.0128x over previous
//
#include <hip/hip_runtime.h>
#include <hip/hip_fp16.h>

#define D 512
#define NTOK 512
#define BINS 64

typedef float v4f __attribute__((ext_vector_type(4)));
typedef int v4i __attribute__((ext_vector_type(4)));
typedef short short8 __attribute__((ext_vector_type(8)));
typedef _Float16 h8 __attribute__((ext_vector_type(8)));
typedef _Float16 h4 __attribute__((ext_vector_type(4)));

// packed f16 tanh-approx gelu: x * sigmoid(1.5957691x + 0.0713548x^3), exp2 form.
// f16 saturation gives correct limits: e=inf -> rcp=0 -> gelu=0 (x<<0);
// e->0 -> rcp(1)=1 -> gelu=x (x>>0).
__device__ __forceinline__ __half2 gelu2(__half2 x) {
    __half2 s = __hmul2(x, x);
    __half2 q = __hmul2(x, __hfma2(s, __float2half2_rn(-0.1029437f),
                                      __float2half2_rn(-2.3022082f)));
    __half2 e = h2exp2(q);
    __half2 r = h2rcp(__hadd2(e, __float2half2_rn(1.0f)));
    return __hmul2(x, r);
}

__device__ __forceinline__ __half2 bc_h2(int v) { return __builtin_bit_cast(__half2, v); }
__device__ __forceinline__ int bc_i(__half2 v) { return __builtin_bit_cast(int, v); }

__device__ __forceinline__ v4i pack8(v4f a, v4f b) {
    h8 o;
    o[0] = (_Float16)a.x; o[1] = (_Float16)a.y; o[2] = (_Float16)a.z; o[3] = (_Float16)a.w;
    o[4] = (_Float16)b.x; o[5] = (_Float16)b.y; o[6] = (_Float16)b.z; o[7] = (_Float16)b.w;
    return __builtin_bit_cast(v4i, o);
}

// Operand packing for the MFMA projection GEMM (and the W2 fragments k_main uses).
// MFMA 16x16x32 f16 fragment layouts (verified lane maps):
//   A-frag: lane l holds A[l&15][(l>>4)*8 + j], j=0..7  (row-major 8 contiguous k)
//   B-frag: lane l holds B[(l>>4)*8 + j][l&15]          (k-major per out-col)
//   D:      col = l&15, row = (l>>4)*4 + reg
// Grid 304, re-balanced for latency spreading (was 112: W1 part had only 64
// blocks = 25% of CUs at 1 wave/SIMD, latency-exposed):
//   b 0..31:    Ap[rb][ks][l] = f16(x[rb*16 + (l&15)][ks*32 + (l>>4)*8 .. +8])
//   b 32..287:  one W1 fragment-slot per thread (64 nb x 16 ks x 64 lanes);
//               W1c[k][n] = W1[(n>=512 ? 512+k : k)*512 + (n&511)] k-major gather,
//               16 lanes read 16 consecutive n of one k-row -> 64B coalesced segs
//   b 288..303: W2 -> Bp fragment pack (unchanged)
__global__ __launch_bounds__(256) void k_pack(const float* __restrict__ x,
                                              const float* __restrict__ W1,
                                              const float* __restrict__ W2,
                                              v4i* __restrict__ Ap,
                                              v4i* __restrict__ Wp,
                                              short8* __restrict__ Bp) {
    const int b = blockIdx.x;
    const int t = threadIdx.x;
    if (b < 32) {            // x fragments: 32 rb x 16 ks x 64 lanes
        const int rb = b;
#pragma unroll
        for (int u = 0; u < 4; ++u) {
            const int e = t + 256 * u;           // 0..1023
            const int l = e & 63, ks = e >> 6;
            const float* src = x + (size_t)(rb * 16 + (l & 15)) * D + ks * 32 + (l >> 4) * 8;
            v4f a = *(const v4f*)src;
            v4f c = *(const v4f*)(src + 4);
            Ap[(size_t)(rb * 16 + ks) * 64 + l] = pack8(a, c);
        }
    } else if (b < 288) {    // W1 fragments: one slot per thread
        const int slot = (b - 32) * 256 + t;     // 0..65535
        const int l = slot & 63;
        const int ks = (slot >> 6) & 15;
        const int nb = slot >> 10;               // 0..63
        const int ng = nb * 16 + (l & 15);       // combined out col 0..1023
        const float* src = W1 + (size_t)((ng >> 9) * D + ks * 32 + (l >> 4) * 8) * D
                              + (ng & 511);
        h8 o;
#pragma unroll
        for (int j = 0; j < 8; ++j) o[j] = (_Float16)src[(size_t)j * D];  // RTE
        Wp[(size_t)(nb * 16 + ks) * 64 + l] = __builtin_bit_cast(v4i, o);
    } else {                 // W2 -> Bp
        const int tid = (b - 288) * 256 + t;     // 0..4095
        const int ll = tid & 63;
        const int nt = (tid >> 6) & 3;
        const int kt = tid >> 8;
        const int colp = nt * 16 + (ll & 15);
        const int krow = kt * 32 + (ll >> 4) * 8;
        short8 v;
#pragma unroll
        for (int u = 0; u < 8; ++u) {
            _Float16 hv = (_Float16)W2[(size_t)(krow + u) * BINS + colp];  // RTE
            v[u] = __builtin_bit_cast(short, hv);
        }
        Bp[tid] = v;
    }
}

// Projection GEMM via MFMA on pre-packed fragments. H[512,1024] = x @ [W1a|W1b].
// Grid 512 = 32 mb (16 token rows) x 16 cb (64 out cols); wave w owns n-frag
// nb = cb*4+w, ONE m-frag (was 2 at grid 256 = 1 block/CU = 1 wave/SIMD,
// latency-exposed; now 2 blocks/CU). No LDS, no barriers: 16B L2-hot fragment
// loads. 16 MFMA/wave, f32 accum, +b1 on the hi half, f16 RTE store.
__global__ __launch_bounds__(256) void k_gemm(const v4i* __restrict__ Ap,
                                              const v4i* __restrict__ Wp,
                                              const float* __restrict__ b1,
                                              _Float16* __restrict__ hi,
                                              _Float16* __restrict__ hj) {
    const int l = threadIdx.x & 63;
    const int w = threadIdx.x >> 6;
    const int c = l & 15;
    const int q = l >> 4;
    const int mb = blockIdx.x >> 4;              // 0..31
    const int cb = blockIdx.x & 15;
    const int nb = cb * 4 + w;

    const v4i* ap = Ap + (size_t)mb * 16 * 64 + l;
    const v4i* wp = Wp + (size_t)nb * 16 * 64 + l;

    v4f acc = {0.f, 0.f, 0.f, 0.f};
#pragma unroll 4
    for (int ks = 0; ks < 16; ++ks) {
        v4i a0 = ap[ks * 64];
        v4i bb = wp[ks * 64];
        acc = __builtin_amdgcn_mfma_f32_16x16x32_f16(__builtin_bit_cast(h8, a0),
                                                     __builtin_bit_cast(h8, bb), acc, 0, 0, 0);
    }

    const int ng = nb * 16 + c;                  // combined out col (one half per nb)
    const float b1v = (ng < D) ? b1[ng] : 0.0f;
    _Float16* dst = (ng < D ? hi : hj) + (ng & 511);
    const int row0 = mb * 16 + q * 4;
#pragma unroll
    for (int r = 0; r < 4; ++r)
        dst[(size_t)(row0 + r) * D] = (_Float16)(acc[r] + b1v);
}

// Main fused kernel: grid 1024; tile 16i x 16j, 4 waves, 4 i-rows/wave.
// BARRIER-FREE: no LDS staging. hi/hj/Bp are L2/L3-resident; per 32-k step each
// wave issues 9 independent 16B loads (hj: 16x64B segments; hi: 16-lane
// broadcast; Bp: per-lane), gelu in packed f16, 16 MFMA. Waves run free —
// the 2-barriers-per-chunk drain (28% stall at 60% VALUBusy) is gone.
__global__ __launch_bounds__(256, 4) void k_main(const __half* __restrict__ hi,
                                                 const __half* __restrict__ hj,
                                                 const v4i* __restrict__ Bp,
                                                 const float* __restrict__ b2,
                                                 float* __restrict__ out) {
    const int l = threadIdx.x & 63;
    const int w = threadIdx.x >> 6;
    const int c = l & 15;   // MFMA col: A m-index (j-offset) / B,D n-offset
    const int q = l >> 4;   // quad: k-group for A/B, row-group for D
    const int ib = (blockIdx.x >> 5) * 16;
    const int j0 = (blockIdx.x & 31) * 16;

    const __half* hjp = hj + (size_t)(j0 + c) * D + q * 8;
    const __half* hip = hi + (size_t)(ib + w * 4) * D + q * 8;
    const v4i* bp = Bp + l;

    v4f acc[4][4] = {};  // [p(i)][nt]

    for (int kt = 0; kt < 16; ++kt) {
        const int ko = kt * 32;
        v4i hjraw = *(const v4i*)(hjp + ko);
        __half2 j0h = bc_h2(hjraw.x), j1h = bc_h2(hjraw.y);
        __half2 j2h = bc_h2(hjraw.z), j3h = bc_h2(hjraw.w);
        v4i bfr[4];
#pragma unroll
        for (int nt = 0; nt < 4; ++nt)
            bfr[nt] = bp[(kt * 4 + nt) * 64];
#pragma unroll
        for (int p = 0; p < 4; ++p) {
            v4i ar = *(const v4i*)(hip + (size_t)p * D + ko);
            __half2 g0 = gelu2(__hadd2(bc_h2(ar.x), j0h));
            __half2 g1 = gelu2(__hadd2(bc_h2(ar.y), j1h));
            __half2 g2 = gelu2(__hadd2(bc_h2(ar.z), j2h));
            __half2 g3 = gelu2(__hadd2(bc_h2(ar.w), j3h));
            v4i ai = {bc_i(g0), bc_i(g1), bc_i(g2), bc_i(g3)};
            h8 af = __builtin_bit_cast(h8, ai);
#pragma unroll
            for (int nt = 0; nt < 4; ++nt)
                acc[p][nt] = __builtin_amdgcn_mfma_f32_16x16x32_f16(
                    af, __builtin_bit_cast(h8, bfr[nt]), acc[p][nt], 0, 0, 0);
        }
    }

    const int i0 = ib + w * 4;
#pragma unroll
    for (int p = 0; p < 4; ++p) {
        const size_t rowbase = ((size_t)(i0 + p) * NTOK + j0 + q * 4) * BINS;
#pragma unroll
        for (int nt = 0; nt < 4; ++nt) {
            const float bb = b2[nt * 16 + c];
            float* op = out + rowbase + nt * 16 + c;
#pragma unroll
            for (int rr = 0; rr < 4; ++rr)
                op[(size_t)rr * BINS] = acc[p][nt][rr] + bb;
        }
    }
}

extern "C" void kernel_launch(void* const* d_in, const int* in_sizes, int n_in,
                              void* d_out, int out_size, void* d_ws, size_t ws_size,
                              hipStream_t stream) {
    const float* x  = (const float*)d_in[0];
    const float* W1 = (const float*)d_in[1];
    const float* b1 = (const float*)d_in[2];
    const float* W2 = (const float*)d_in[3];
    const float* b2 = (const float*)d_in[4];
    float* out = (float*)d_out;

    char* ws = (char*)d_ws;
    __half* hi = (__half*)ws;                          // 512 KB
    __half* hj = (__half*)(ws + (512u << 10));         // 512 KB
    short8* Bp = (short8*)(ws + (1u << 20));           // 64 KB
    v4i*    Ap = (v4i*)(ws + (1u << 20) + (64u << 10));            // 512 KB
    v4i*    Wp = (v4i*)(ws + (1u << 20) + (64u << 10) + (512u << 10));  // 1 MB

    k_pack<<<304, 256, 0, stream>>>(x, W1, W2, Ap, Wp, Bp);
    k_gemm<<<512, 256, 0, stream>>>(Ap, Wp, b1, (_Float16*)hi, (_Float16*)hj);
    k_main<<<1024, 256, 0, stream>>>(hi, hj, (const v4i*)Bp, b2, out);
}